// Round 1
// baseline (959.668 us; speedup 1.0000x reference)
//
#include <hip/hip_runtime.h>
#include <hip/hip_bf16.h>
#include <math.h>

// ---------------------------------------------------------------------------
// YatNMN: out[b,s,o] = scale * ( y^2/(||x||^2+||w||^2-2y+eps) + bias[o] )
//   y = x @ kernel,  x:[16384,2048] f32, kernel:[2048,8192] f32, out f32.
// Strategy: demote to bf16, MFMA GEMM (m97 128x128 structure), fp32 norms,
// fused epilogue. Workspace layout (needs ~97 MiB):
//   [0)              xbf  : 16384*2048 bf16  (67,108,864 B)
//   [67108864)       ktb  : 8192*2048 bf16 (kernel^T)   (33,554,432 B)
//   [100663296)      xs   : 16384 f32 row norms         (65,536 B)
//   [100728832)      ks   : 8192 f32 col norms          (32,768 B)
//   [100761600)      kpart: 16*8192 f32 partials        (524,288 B)
// ---------------------------------------------------------------------------

#define EPS_F (1.0f / 137.0f)
#define M_DIM 16384
#define N_DIM 8192
#define K_DIM 2048

typedef __attribute__((ext_vector_type(8))) short short8;
typedef __attribute__((ext_vector_type(4))) float f32x4;

__device__ __forceinline__ unsigned short f2bf(float f) {
  // round-to-nearest-even f32 -> bf16 (inputs are finite)
  unsigned int u = __float_as_uint(f);
  u += 0x7fffu + ((u >> 16) & 1u);
  return (unsigned short)(u >> 16);
}

typedef __attribute__((address_space(1))) const unsigned int as1_cuint;
typedef __attribute__((address_space(3))) unsigned int as3_uint;

__device__ __forceinline__ void gload16(const void* g, void* lds_wave_base) {
  // async global->LDS, 16B per lane; LDS dest = wave-uniform base + lane*16
  __builtin_amdgcn_global_load_lds((as1_cuint*)g, (as3_uint*)lds_wave_base, 16, 0, 0);
}

// --------------------------- prologue kernels ------------------------------

// x f32 -> bf16, fused row sum-of-squares. One block per row (2048 elems).
__global__ __launch_bounds__(256) void k_conv_x(const float* __restrict__ x,
                                                unsigned short* __restrict__ xbf,
                                                float* __restrict__ xs) {
  const int row = blockIdx.x;
  const int t = threadIdx.x;
  const float4* xr = (const float4*)(x + (size_t)row * K_DIM);
  ushort4* orow = (ushort4*)(xbf + (size_t)row * K_DIM);
  float s = 0.f;
#pragma unroll
  for (int i = 0; i < 2; ++i) {
    float4 v = xr[t + i * 256];
    s += v.x * v.x + v.y * v.y + v.z * v.z + v.w * v.w;
    ushort4 o;
    o.x = f2bf(v.x); o.y = f2bf(v.y); o.z = f2bf(v.z); o.w = f2bf(v.w);
    orow[t + i * 256] = o;
  }
#pragma unroll
  for (int off = 32; off > 0; off >>= 1) s += __shfl_down(s, off, 64);
  __shared__ float red[4];
  if ((t & 63) == 0) red[t >> 6] = s;
  __syncthreads();
  if (t == 0) xs[row] = red[0] + red[1] + red[2] + red[3];
}

// kernel [K][N] f32 -> kernel^T [N][K] bf16 (32x32 LDS transpose tiles)
__global__ __launch_bounds__(256) void k_conv_kT(const float* __restrict__ w,
                                                 unsigned short* __restrict__ bt) {
  __shared__ float tile[32][33];
  const int tx = threadIdx.x;  // 32
  const int ty = threadIdx.y;  // 8
  const int n0 = blockIdx.x * 32;
  const int k0 = blockIdx.y * 32;
#pragma unroll
  for (int j = 0; j < 32; j += 8)
    tile[ty + j][tx] = w[(size_t)(k0 + ty + j) * N_DIM + n0 + tx];
  __syncthreads();
#pragma unroll
  for (int j = 0; j < 32; j += 8)
    bt[(size_t)(n0 + ty + j) * K_DIM + k0 + tx] = f2bf(tile[tx][ty + j]);
}

// ||w_col||^2 stage 1: partial sums over 128-row stripes
__global__ __launch_bounds__(256) void k_ksq_part(const float* __restrict__ w,
                                                  float* __restrict__ kpart) {
  const int col = blockIdx.x * 256 + threadIdx.x;
  const int kb = blockIdx.y;
  float s = 0.f;
#pragma unroll 4
  for (int k = kb * 128; k < kb * 128 + 128; ++k) {
    float v = w[(size_t)k * N_DIM + col];
    s += v * v;
  }
  kpart[kb * N_DIM + col] = s;
}

__global__ __launch_bounds__(256) void k_ksq_fin(const float* __restrict__ kpart,
                                                 float* __restrict__ ks) {
  const int col = blockIdx.x * 256 + threadIdx.x;
  float s = 0.f;
#pragma unroll
  for (int kb = 0; kb < 16; ++kb) s += kpart[kb * N_DIM + col];
  ks[col] = s;
}

// ------------------------------- GEMM --------------------------------------
// 128x128 tile, BK=64, 256 threads = 4 waves in 2x2, each wave 64x64 out.
// A: xbf [M][K] row-major bf16. B: ktb [N][K] row-major bf16 (= kernel^T).
// LDS tiles [128 rows][64 k] bf16 = 16 KiB each, XOR-swizzled:
//   logical (row, byte_col) stored at row*128 + (byte_col ^ ((row&7)<<4)).
// global_load_lds writes linearly, so the *source* address carries the
// inverse swizzle (same involution); ds_read applies it again.
__global__ __launch_bounds__(256) void k_gemm(const unsigned short* __restrict__ A,
                                              const unsigned short* __restrict__ B,
                                              const float* __restrict__ xs,
                                              const float* __restrict__ ks,
                                              const float* __restrict__ bias,
                                              const float* __restrict__ alpha,
                                              float* __restrict__ out) {
  __shared__ __align__(16) char sA[16384];
  __shared__ __align__(16) char sB[16384];

  const int t = threadIdx.x;
  const int lane = t & 63;
  const int waveBase = t & 192;  // wave_id*64
  const int wid = t >> 6;
  const int wr = wid >> 1, wc = wid & 1;
  const int lr = lane & 15;   // fragment row (A's m / B^T's n / C's col)
  const int kh = lane >> 4;   // k-half-slot: k offset kh*8
  const int swz = (lr & 7) << 4;

  // XCD-aware bijective swizzle: 8192 blocks % 8 XCDs == 0
  const int bid = blockIdx.x;
  const int sw = (bid & 7) * 1024 + (bid >> 3);
  const int tn = sw & 63;
  const int tm = sw >> 6;
  const size_t rowM0 = (size_t)tm * 128;
  const size_t colN0 = (size_t)tn * 128;

  // staging: 1024 16B-chunks per tile; thread t takes chunks i*256+t.
  int cRow[4], cLc[4];
#pragma unroll
  for (int i = 0; i < 4; ++i) {
    const int c = i * 256 + t;
    cRow[i] = c >> 3;
    cLc[i] = (c & 7) ^ (cRow[i] & 7);  // inverse-swizzled source chunk
  }

  f32x4 acc[4][4] = {};

  for (int k0 = 0; k0 < K_DIM; k0 += 64) {
    __syncthreads();  // previous iter's ds_reads complete before overwrite
#pragma unroll
    for (int i = 0; i < 4; ++i) {
      const unsigned short* gA = A + (rowM0 + cRow[i]) * K_DIM + k0 + cLc[i] * 8;
      gload16(gA, sA + (size_t)(i * 256 + waveBase) * 16);
      const unsigned short* gB = B + (colN0 + cRow[i]) * K_DIM + k0 + cLc[i] * 8;
      gload16(gB, sB + (size_t)(i * 256 + waveBase) * 16);
    }
    __syncthreads();  // compiler drains vmcnt(0) before s_barrier

#pragma unroll
    for (int kk = 0; kk < 2; ++kk) {
      short8 a[4], b[4];
#pragma unroll
      for (int m = 0; m < 4; ++m) {
        const int row = wr * 64 + m * 16 + lr;
        a[m] = *(const short8*)(sA + row * 128 + ((kk * 64 + kh * 16) ^ swz));
      }
#pragma unroll
      for (int n = 0; n < 4; ++n) {
        const int row = wc * 64 + n * 16 + lr;
        b[n] = *(const short8*)(sB + row * 128 + ((kk * 64 + kh * 16) ^ swz));
      }
#pragma unroll
      for (int m = 0; m < 4; ++m)
#pragma unroll
        for (int n = 0; n < 4; ++n)
          acc[m][n] = __builtin_amdgcn_mfma_f32_16x16x32_bf16(a[m], b[n], acc[m][n], 0, 0, 0);
    }
  }

  // fused Yat epilogue. C/D layout: col = lane&15, row = (lane>>4)*4 + reg.
  const float scale = powf(sqrtf(8192.0f) / log1pf(8192.0f), alpha[0]);
#pragma unroll
  for (int m = 0; m < 4; ++m) {
#pragma unroll
    for (int r = 0; r < 4; ++r) {
      const size_t grow = rowM0 + wr * 64 + m * 16 + kh * 4 + r;
      const float xq = xs[grow];
      float* orow = out + grow * N_DIM;
#pragma unroll
      for (int n = 0; n < 4; ++n) {
        const int gcol = (int)colN0 + wc * 64 + n * 16 + lr;
        const float y = acc[m][n][r];
        const float d = xq + ks[gcol] - 2.0f * y + EPS_F;
        const float v = y * y * __builtin_amdgcn_rcpf(d);
        orow[gcol] = (v + bias[gcol]) * scale;
      }
    }
  }
}

// ------------------------------ launch -------------------------------------

extern "C" void kernel_launch(void* const* d_in, const int* in_sizes, int n_in,
                              void* d_out, int out_size, void* d_ws, size_t ws_size,
                              hipStream_t stream) {
  const float* x     = (const float*)d_in[0];
  const float* w     = (const float*)d_in[1];
  const float* bias  = (const float*)d_in[2];
  const float* alpha = (const float*)d_in[3];
  float* out = (float*)d_out;
  char* ws = (char*)d_ws;

  unsigned short* xbf = (unsigned short*)(ws);
  unsigned short* ktb = (unsigned short*)(ws + 67108864);
  float* xs    = (float*)(ws + 100663296);
  float* ks    = (float*)(ws + 100728832);
  float* kpart = (float*)(ws + 100761600);
  // requires ws_size >= 101,285,888 bytes

  k_conv_x<<<M_DIM, 256, 0, stream>>>(x, xbf, xs);
  k_conv_kT<<<dim3(N_DIM / 32, K_DIM / 32), dim3(32, 8), 0, stream>>>(w, ktb);
  k_ksq_part<<<dim3(N_DIM / 256, 16), 256, 0, stream>>>(w, kpart);
  k_ksq_fin<<<N_DIM / 256, 256, 0, stream>>>(kpart, ks);
  k_gemm<<<(M_DIM / 128) * (N_DIM / 128), 256, 0, stream>>>(xbf, ktb, xs, ks, bias, alpha, out);
}

// Round 3
// 636.192 us; speedup vs baseline: 1.5085x; 1.5085x over previous
//
#include <hip/hip_runtime.h>
#include <hip/hip_bf16.h>
#include <math.h>

// ---------------------------------------------------------------------------
// YatNMN: out = scale * ( y^2/(||x||^2+||w||^2-2y+eps) + bias ), y = x@W
// x:[16384,2048] f32, W:[2048,8192] f32, out f32 [16384,8192].
// R3 = R2 resubmit (R2 bench died to infra: UnresponsiveContainer).
// 256x256 8-phase GEMM (T2 swizzle + T3/T4 counted-vmcnt phases + T5
// setprio), bf16 MFMA, fused Yat epilogue. Workspace (~97 MiB):
//   [0)          xbf  : 16384*2048 bf16
//   [67108864)   ktb  : 8192*2048 bf16 (W^T)
//   [100663296)  xs   : 16384 f32 row norms
//   [100728832)  ks   : 8192 f32 col norms
//   [100761600)  kpart: 16*8192 f32 partials
// ---------------------------------------------------------------------------

#define EPS_F (1.0f / 137.0f)
#define M_DIM 16384
#define N_DIM 8192
#define K_DIM 2048

typedef __attribute__((ext_vector_type(8))) short short8;
typedef __attribute__((ext_vector_type(4))) float f32x4;

__device__ __forceinline__ unsigned short f2bf(float f) {
  unsigned int u = __float_as_uint(f);
  u += 0x7fffu + ((u >> 16) & 1u);
  return (unsigned short)(u >> 16);
}

typedef __attribute__((address_space(1))) const unsigned int as1_cuint;
typedef __attribute__((address_space(3))) unsigned int as3_uint;

__device__ __forceinline__ void gload16(const void* g, void* lds_wave_base) {
  __builtin_amdgcn_global_load_lds((as1_cuint*)g, (as3_uint*)lds_wave_base, 16, 0, 0);
}

// --------------------------- prologue kernels ------------------------------

__global__ __launch_bounds__(256) void k_conv_x(const float* __restrict__ x,
                                                unsigned short* __restrict__ xbf,
                                                float* __restrict__ xs) {
  const int row = blockIdx.x;
  const int t = threadIdx.x;
  const float4* xr = (const float4*)(x + (size_t)row * K_DIM);
  ushort4* orow = (ushort4*)(xbf + (size_t)row * K_DIM);
  float s = 0.f;
#pragma unroll
  for (int i = 0; i < 2; ++i) {
    float4 v = xr[t + i * 256];
    s += v.x * v.x + v.y * v.y + v.z * v.z + v.w * v.w;
    ushort4 o;
    o.x = f2bf(v.x); o.y = f2bf(v.y); o.z = f2bf(v.z); o.w = f2bf(v.w);
    orow[t + i * 256] = o;
  }
#pragma unroll
  for (int off = 32; off > 0; off >>= 1) s += __shfl_down(s, off, 64);
  __shared__ float red[4];
  if ((t & 63) == 0) red[t >> 6] = s;
  __syncthreads();
  if (t == 0) xs[row] = red[0] + red[1] + red[2] + red[3];
}

__global__ __launch_bounds__(256) void k_conv_kT(const float* __restrict__ w,
                                                 unsigned short* __restrict__ bt) {
  __shared__ float tile[32][33];
  const int tx = threadIdx.x;
  const int ty = threadIdx.y;
  const int n0 = blockIdx.x * 32;
  const int k0 = blockIdx.y * 32;
#pragma unroll
  for (int j = 0; j < 32; j += 8)
    tile[ty + j][tx] = w[(size_t)(k0 + ty + j) * N_DIM + n0 + tx];
  __syncthreads();
#pragma unroll
  for (int j = 0; j < 32; j += 8)
    bt[(size_t)(n0 + ty + j) * K_DIM + k0 + tx] = f2bf(tile[tx][ty + j]);
}

__global__ __launch_bounds__(256) void k_ksq_part(const float* __restrict__ w,
                                                  float* __restrict__ kpart) {
  const int col = blockIdx.x * 256 + threadIdx.x;
  const int kb = blockIdx.y;
  float s = 0.f;
#pragma unroll 4
  for (int k = kb * 128; k < kb * 128 + 128; ++k) {
    float v = w[(size_t)k * N_DIM + col];
    s += v * v;
  }
  kpart[kb * N_DIM + col] = s;
}

__global__ __launch_bounds__(256) void k_ksq_fin(const float* __restrict__ kpart,
                                                 float* __restrict__ ks) {
  const int col = blockIdx.x * 256 + threadIdx.x;
  float s = 0.f;
#pragma unroll
  for (int kb = 0; kb < 16; ++kb) s += kpart[kb * N_DIM + col];
  ks[col] = s;
}

// ------------------------------- GEMM 256x256 8-phase ----------------------
// A: xbf [M][K] bf16.  B: ktb [N][K] bf16.  8 waves: wr=wid>>2 (M), wc=wid&3.
// LDS: sA[2][256 rows][128B], sB[2][256][128B] = 128 KiB, XOR swizzle
//   byte_col ^= (row&7)<<4 applied on ds_read; inverse on the global source
//   of global_load_lds (LDS written linearly).
// Per iteration: tiles 2it (buf0, phases 0-3) and 2it+1 (buf1, phases 4-7).
// Staging (2 loads/phase) targets only regions freed by the previous phase:
//   ph0: tile 2it+1 A-stripe3 + B-load3 -> buf1   (completes T1)
//   ph1-4: tile 2it+2 A-stripe0..3 + B-load0..3 -> buf0
//   ph5-7: tile 2it+3 A-stripe0..2 + B-load0..2 -> buf1
// vmcnt(8) before compute at phases 0 and 4 (tile fully landed; 8 newer
// loads stay in flight). Never drained to 0 inside the loop.

#define MFMA_OP(d, va, vb) \
  d = __builtin_amdgcn_mfma_f32_16x16x32_bf16(va, vb, d, 0, 0, 0)

#define FENCE asm volatile("" ::: "memory")
#define BAR do { FENCE; __builtin_amdgcn_s_barrier(); FENCE; } while (0)
#define VMCNT8 asm volatile("s_waitcnt vmcnt(8)" ::: "memory")

__global__ __launch_bounds__(512) void k_gemm(const unsigned short* __restrict__ A,
                                              const unsigned short* __restrict__ B,
                                              const float* __restrict__ xs,
                                              const float* __restrict__ ks,
                                              const float* __restrict__ bias,
                                              const float* __restrict__ alpha,
                                              float* __restrict__ out) {
  __shared__ __align__(16) char lds[131072];
  char* sA = lds;
  char* sB = lds + 65536;

  const int t = threadIdx.x;
  const int lane = t & 63;
  const int wid = t >> 6;
  const int wr = wid >> 2;  // 0..1 (M)
  const int wc = wid & 3;   // 0..3 (N)
  const int lr = lane & 15;
  const int kh = lane >> 4;
  const int swz = (lr & 7) << 4;

  // XCD-aware bijective block swizzle: 2048 blocks % 8 == 0
  const int bid = blockIdx.x;
  const int sw = (bid & 7) * 256 + (bid >> 3);
  const int tm = sw >> 5;  // 64 M-tiles
  const int tn = sw & 31;  // 32 N-tiles
  const size_t rowM0 = (size_t)tm * 256;
  const size_t colN0 = (size_t)tn * 256;

  // staging geometry: per load instr, wave w covers 8 rows (1KB LDS linear)
  const int l8 = lane >> 3;                       // 0..7
  const int col16 = (lane & 7) ^ (l8 & 7);        // inverse-swizzled 16B slot
  const int rA_base = (wid < 4) ? wid * 8 : 128 + (wid - 4) * 8;
  const unsigned short* gA0 = A + (rowM0 + rA_base + l8) * K_DIM + col16 * 8;
  const unsigned short* gB0 = B + (colN0 + wid * 8 + l8) * K_DIM + col16 * 8;

// stage A stripe s (rows [32s,32s+32) U [128+32s,128+32s+32)) of tile at
// k-elem offset ko into buf b; B load j (rows [64j,64j+64)).
#define STAGE_A(b, s, ko) \
  gload16(gA0 + (size_t)(s) * 32 * K_DIM + (ko), \
          sA + (b) * 32768 + (rA_base + (s) * 32) * 128)
#define STAGE_B(b, j, ko) \
  gload16(gB0 + (size_t)(j) * 64 * K_DIM + (ko), \
          sB + (b) * 32768 + ((j) * 64 + wid * 8) * 128)

#define RD_A(b, m, kk) \
  (*(const short8*)(sA + (b) * 32768 + (wr * 128 + (m) * 16 + lr) * 128 + \
                    (((kk) * 64 + kh * 16) ^ swz)))
#define RD_B(b, n, kk) \
  (*(const short8*)(sB + (b) * 32768 + (wc * 64 + (n) * 16 + lr) * 128 + \
                    (((kk) * 64 + kh * 16) ^ swz)))

  f32x4 acc[8][4] = {};
  short8 a00, a01, a10, a11;
  short8 b0[4], b1[4];

#define MFMA16(mb) do { \
  __builtin_amdgcn_s_setprio(1); \
  MFMA_OP(acc[mb][0], a00, b0[0]); MFMA_OP(acc[mb][1], a00, b0[1]); \
  MFMA_OP(acc[mb][2], a00, b0[2]); MFMA_OP(acc[mb][3], a00, b0[3]); \
  MFMA_OP(acc[(mb)+1][0], a10, b0[0]); MFMA_OP(acc[(mb)+1][1], a10, b0[1]); \
  MFMA_OP(acc[(mb)+1][2], a10, b0[2]); MFMA_OP(acc[(mb)+1][3], a10, b0[3]); \
  MFMA_OP(acc[mb][0], a01, b1[0]); MFMA_OP(acc[mb][1], a01, b1[1]); \
  MFMA_OP(acc[mb][2], a01, b1[2]); MFMA_OP(acc[mb][3], a01, b1[3]); \
  MFMA_OP(acc[(mb)+1][0], a11, b1[0]); MFMA_OP(acc[(mb)+1][1], a11, b1[1]); \
  MFMA_OP(acc[(mb)+1][2], a11, b1[2]); MFMA_OP(acc[(mb)+1][3], a11, b1[3]); \
  __builtin_amdgcn_s_setprio(0); \
} while (0)

// first phase of a tile: stage was issued by caller; wait tile landed, then
// 12 ds_reads (8 B + 4 A), MFMA m={0,1}.
#define PHASE_FIRST(b) do { \
  VMCNT8; BAR; \
  b0[0] = RD_B(b, 0, 0); b0[1] = RD_B(b, 1, 0); b0[2] = RD_B(b, 2, 0); b0[3] = RD_B(b, 3, 0); \
  b1[0] = RD_B(b, 0, 1); b1[1] = RD_B(b, 1, 1); b1[2] = RD_B(b, 2, 1); b1[3] = RD_B(b, 3, 1); \
  a00 = RD_A(b, 0, 0); a01 = RD_A(b, 0, 1); a10 = RD_A(b, 1, 0); a11 = RD_A(b, 1, 1); \
  MFMA16(0); \
  BAR; \
} while (0)

// later phase: 4 A ds_reads + stage, barrier, MFMA m={mb,mb+1}.
#define PHASE_REST(b, mb, STG) do { \
  a00 = RD_A(b, mb, 0); a01 = RD_A(b, mb, 1); \
  a10 = RD_A(b, (mb)+1, 0); a11 = RD_A(b, (mb)+1, 1); \
  STG; \
  BAR; \
  MFMA16(mb); \
  BAR; \
} while (0)

  // prologue: tile0 (8 loads -> buf0), tile1 partial (6 loads -> buf1)
  STAGE_A(0, 0, 0); STAGE_B(0, 0, 0);
  STAGE_A(0, 1, 0); STAGE_B(0, 1, 0);
  STAGE_A(0, 2, 0); STAGE_B(0, 2, 0);
  STAGE_A(0, 3, 0); STAGE_B(0, 3, 0);
  STAGE_A(1, 0, 64); STAGE_B(1, 0, 64);
  STAGE_A(1, 1, 64); STAGE_B(1, 1, 64);
  STAGE_A(1, 2, 64); STAGE_B(1, 2, 64);

#pragma unroll 1
  for (int it = 0; it < 16; ++it) {
    const int kT1 = it * 128 + 64;                    // tile 2it+1 (real)
    const int kS0 = (it < 15) ? it * 128 + 128 : 0;   // tile 2it+2 (clamped)
    const int kS1 = (it < 15) ? it * 128 + 192 : 0;   // tile 2it+3 (clamped)
    // phase 0: finish staging T1, compute tile 2it m=0,1 from buf0
    STAGE_A(1, 3, kT1); STAGE_B(1, 3, kT1);
    PHASE_FIRST(0);
    // phases 1-3
    PHASE_REST(0, 2, (STAGE_A(0, 0, kS0), STAGE_B(0, 0, kS0)));
    PHASE_REST(0, 4, (STAGE_A(0, 1, kS0), STAGE_B(0, 1, kS0)));
    PHASE_REST(0, 6, (STAGE_A(0, 2, kS0), STAGE_B(0, 2, kS0)));
    // phase 4: finish staging S0, compute tile 2it+1 m=0,1 from buf1
    STAGE_A(0, 3, kS0); STAGE_B(0, 3, kS0);
    PHASE_FIRST(1);
    // phases 5-7
    PHASE_REST(1, 2, (STAGE_A(1, 0, kS1), STAGE_B(1, 0, kS1)));
    PHASE_REST(1, 4, (STAGE_A(1, 1, kS1), STAGE_B(1, 1, kS1)));
    PHASE_REST(1, 6, (STAGE_A(1, 2, kS1), STAGE_B(1, 2, kS1)));
  }

  // drain trailing (garbage) stages before LDS goes out of scope
  asm volatile("s_waitcnt vmcnt(0)" ::: "memory");

  // fused Yat epilogue. C/D: col = lane&15 (N), row = (lane>>4)*4 + reg (M).
  const float scale = powf(sqrtf(8192.0f) / log1pf(8192.0f), alpha[0]);
#pragma unroll
  for (int m = 0; m < 8; ++m) {
#pragma unroll
    for (int r = 0; r < 4; ++r) {
      const size_t grow = rowM0 + wr * 128 + m * 16 + kh * 4 + r;
      const float xq = xs[grow];
      float* orow = out + grow * N_DIM;
#pragma unroll
      for (int n = 0; n < 4; ++n) {
        const int gcol = (int)colN0 + wc * 64 + n * 16 + lr;
        const float y = acc[m][n][r];
        const float d = xq + ks[gcol] - 2.0f * y + EPS_F;
        const float v = y * y * __builtin_amdgcn_rcpf(d);
        orow[gcol] = (v + bias[gcol]) * scale;
      }
    }
  }
}

// ------------------------------ launch -------------------------------------

extern "C" void kernel_launch(void* const* d_in, const int* in_sizes, int n_in,
                              void* d_out, int out_size, void* d_ws, size_t ws_size,
                              hipStream_t stream) {
  const float* x     = (const float*)d_in[0];
  const float* w     = (const float*)d_in[1];
  const float* bias  = (const float*)d_in[2];
  const float* alpha = (const float*)d_in[3];
  float* out = (float*)d_out;
  char* ws = (char*)d_ws;

  unsigned short* xbf = (unsigned short*)(ws);
  unsigned short* ktb = (unsigned short*)(ws + 67108864);
  float* xs    = (float*)(ws + 100663296);
  float* ks    = (float*)(ws + 100728832);
  float* kpart = (float*)(ws + 100761600);

  k_conv_x<<<M_DIM, 256, 0, stream>>>(x, xbf, xs);
  k_conv_kT<<<dim3(N_DIM / 32, K_DIM / 32), dim3(32, 8), 0, stream>>>(w, ktb);
  k_ksq_part<<<dim3(N_DIM / 256, 16), 256, 0, stream>>>(w, kpart);
  k_ksq_fin<<<N_DIM / 256, 256, 0, stream>>>(kpart, ks);
  k_gemm<<<(M_DIM / 256) * (N_DIM / 256), 512, 0, stream>>>(xbf, ktb, xs, ks, bias, alpha, out);
}

// Round 4
// 573.651 us; speedup vs baseline: 1.6729x; 1.1090x over previous
//
#include <hip/hip_runtime.h>
#include <hip/hip_bf16.h>
#include <math.h>

// ---------------------------------------------------------------------------
// YatNMN: out = scale * ( y^2/(||x||^2+||w||^2-2y+eps) + bias ), y = x@W
// x:[16384,2048] f32, W:[2048,8192] f32, out f32 [16384,8192].
// R4 = R3 + 2D-chunked XCD swizzle (each XCD: 16x16 tile region walked in
// 4tm x 8tn chunks of 32 blocks) to cut L3/HBM panel refetch ~2.7x.
// 256x256 8-phase GEMM (T2 swizzle + T3/T4 counted-vmcnt + T5 setprio),
// bf16 MFMA, fused Yat epilogue. Workspace (~97 MiB):
//   [0)          xbf  : 16384*2048 bf16
//   [67108864)   ktb  : 8192*2048 bf16 (W^T)
//   [100663296)  xs   : 16384 f32 row norms
//   [100728832)  ks   : 8192 f32 col norms
//   [100761600)  kpart: 16*8192 f32 partials
// ---------------------------------------------------------------------------

#define EPS_F (1.0f / 137.0f)
#define M_DIM 16384
#define N_DIM 8192
#define K_DIM 2048

typedef __attribute__((ext_vector_type(8))) short short8;
typedef __attribute__((ext_vector_type(4))) float f32x4;

__device__ __forceinline__ unsigned short f2bf(float f) {
  unsigned int u = __float_as_uint(f);
  u += 0x7fffu + ((u >> 16) & 1u);
  return (unsigned short)(u >> 16);
}

typedef __attribute__((address_space(1))) const unsigned int as1_cuint;
typedef __attribute__((address_space(3))) unsigned int as3_uint;

__device__ __forceinline__ void gload16(const void* g, void* lds_wave_base) {
  __builtin_amdgcn_global_load_lds((as1_cuint*)g, (as3_uint*)lds_wave_base, 16, 0, 0);
}

// --------------------------- prologue kernels ------------------------------

__global__ __launch_bounds__(256) void k_conv_x(const float* __restrict__ x,
                                                unsigned short* __restrict__ xbf,
                                                float* __restrict__ xs) {
  const int row = blockIdx.x;
  const int t = threadIdx.x;
  const float4* xr = (const float4*)(x + (size_t)row * K_DIM);
  ushort4* orow = (ushort4*)(xbf + (size_t)row * K_DIM);
  float s = 0.f;
#pragma unroll
  for (int i = 0; i < 2; ++i) {
    float4 v = xr[t + i * 256];
    s += v.x * v.x + v.y * v.y + v.z * v.z + v.w * v.w;
    ushort4 o;
    o.x = f2bf(v.x); o.y = f2bf(v.y); o.z = f2bf(v.z); o.w = f2bf(v.w);
    orow[t + i * 256] = o;
  }
#pragma unroll
  for (int off = 32; off > 0; off >>= 1) s += __shfl_down(s, off, 64);
  __shared__ float red[4];
  if ((t & 63) == 0) red[t >> 6] = s;
  __syncthreads();
  if (t == 0) xs[row] = red[0] + red[1] + red[2] + red[3];
}

__global__ __launch_bounds__(256) void k_conv_kT(const float* __restrict__ w,
                                                 unsigned short* __restrict__ bt) {
  __shared__ float tile[32][33];
  const int tx = threadIdx.x;
  const int ty = threadIdx.y;
  const int n0 = blockIdx.x * 32;
  const int k0 = blockIdx.y * 32;
#pragma unroll
  for (int j = 0; j < 32; j += 8)
    tile[ty + j][tx] = w[(size_t)(k0 + ty + j) * N_DIM + n0 + tx];
  __syncthreads();
#pragma unroll
  for (int j = 0; j < 32; j += 8)
    bt[(size_t)(n0 + ty + j) * K_DIM + k0 + tx] = f2bf(tile[tx][ty + j]);
}

__global__ __launch_bounds__(256) void k_ksq_part(const float* __restrict__ w,
                                                  float* __restrict__ kpart) {
  const int col = blockIdx.x * 256 + threadIdx.x;
  const int kb = blockIdx.y;
  float s = 0.f;
#pragma unroll 4
  for (int k = kb * 128; k < kb * 128 + 128; ++k) {
    float v = w[(size_t)k * N_DIM + col];
    s += v * v;
  }
  kpart[kb * N_DIM + col] = s;
}

__global__ __launch_bounds__(256) void k_ksq_fin(const float* __restrict__ kpart,
                                                 float* __restrict__ ks) {
  const int col = blockIdx.x * 256 + threadIdx.x;
  float s = 0.f;
#pragma unroll
  for (int kb = 0; kb < 16; ++kb) s += kpart[kb * N_DIM + col];
  ks[col] = s;
}

// ------------------------------- GEMM 256x256 8-phase ----------------------
// A: xbf [M][K] bf16.  B: ktb [N][K] bf16.  8 waves: wr=wid>>2 (M), wc=wid&3.
// LDS: sA[2][256 rows][128B], sB[2][256][128B] = 128 KiB, XOR swizzle
//   byte_col ^= (row&7)<<4 applied on ds_read; inverse on the global source
//   of global_load_lds (LDS written linearly).
// Per iteration: tiles 2it (buf0, phases 0-3) and 2it+1 (buf1, phases 4-7).
// Staging (2 loads/phase) targets only regions freed by the previous phase:
//   ph0: tile 2it+1 A-stripe3 + B-load3 -> buf1   (completes T1)
//   ph1-4: tile 2it+2 A-stripe0..3 + B-load0..3 -> buf0
//   ph5-7: tile 2it+3 A-stripe0..2 + B-load0..2 -> buf1
// vmcnt(8) before compute at phases 0 and 4 (tile fully landed; 8 newer
// loads stay in flight). Never drained to 0 inside the loop.

#define MFMA_OP(d, va, vb) \
  d = __builtin_amdgcn_mfma_f32_16x16x32_bf16(va, vb, d, 0, 0, 0)

#define FENCE asm volatile("" ::: "memory")
#define BAR do { FENCE; __builtin_amdgcn_s_barrier(); FENCE; } while (0)
#define VMCNT8 asm volatile("s_waitcnt vmcnt(8)" ::: "memory")

__global__ __launch_bounds__(512) void k_gemm(const unsigned short* __restrict__ A,
                                              const unsigned short* __restrict__ B,
                                              const float* __restrict__ xs,
                                              const float* __restrict__ ks,
                                              const float* __restrict__ bias,
                                              const float* __restrict__ alpha,
                                              float* __restrict__ out) {
  __shared__ __align__(16) char lds[131072];
  char* sA = lds;
  char* sB = lds + 65536;

  const int t = threadIdx.x;
  const int lane = t & 63;
  const int wid = t >> 6;
  const int wr = wid >> 2;  // 0..1 (M)
  const int wc = wid & 3;   // 0..3 (N)
  const int lr = lane & 15;
  const int kh = lane >> 4;
  const int swz = (lr & 7) << 4;

  // 2D-chunked XCD swizzle (bijective: 2048 = 8 xcd * 8 chunks * 32).
  // XCD x owns a 16tm x 16tn region; walked in 4tm x 8tn chunks of 32
  // blocks (= one XCD's concurrent block capacity). Concurrent working
  // set per XCD: 4 A-panels + 8 B-panels = 12 MB (vs 33 MB for row-major).
  const int bid = blockIdx.x;
  const int xcd = bid & 7;
  const int sub = bid >> 3;   // 0..255 within XCD
  const int c   = sub >> 5;   // chunk 0..7 (4 tm-bands x 2 tn-halves)
  const int tm = ((xcd >> 1) << 4) + ((c >> 1) << 2) + ((sub >> 3) & 3);
  const int tn = ((xcd & 1) << 4) + ((c & 1) << 3) + (sub & 7);
  const size_t rowM0 = (size_t)tm * 256;
  const size_t colN0 = (size_t)tn * 256;

  // staging geometry: per load instr, wave w covers 8 rows (1KB LDS linear)
  const int l8 = lane >> 3;                       // 0..7
  const int col16 = (lane & 7) ^ (l8 & 7);        // inverse-swizzled 16B slot
  const int rA_base = (wid < 4) ? wid * 8 : 128 + (wid - 4) * 8;
  const unsigned short* gA0 = A + (rowM0 + rA_base + l8) * K_DIM + col16 * 8;
  const unsigned short* gB0 = B + (colN0 + wid * 8 + l8) * K_DIM + col16 * 8;

// stage A stripe s (rows [32s,32s+32) U [128+32s,128+32s+32)) of tile at
// k-elem offset ko into buf b; B load j (rows [64j,64j+64)).
#define STAGE_A(b, s, ko) \
  gload16(gA0 + (size_t)(s) * 32 * K_DIM + (ko), \
          sA + (b) * 32768 + (rA_base + (s) * 32) * 128)
#define STAGE_B(b, j, ko) \
  gload16(gB0 + (size_t)(j) * 64 * K_DIM + (ko), \
          sB + (b) * 32768 + ((j) * 64 + wid * 8) * 128)

#define RD_A(b, m, kk) \
  (*(const short8*)(sA + (b) * 32768 + (wr * 128 + (m) * 16 + lr) * 128 + \
                    (((kk) * 64 + kh * 16) ^ swz)))
#define RD_B(b, n, kk) \
  (*(const short8*)(sB + (b) * 32768 + (wc * 64 + (n) * 16 + lr) * 128 + \
                    (((kk) * 64 + kh * 16) ^ swz)))

  f32x4 acc[8][4] = {};
  short8 a00, a01, a10, a11;
  short8 b0[4], b1[4];

#define MFMA16(mb) do { \
  __builtin_amdgcn_s_setprio(1); \
  MFMA_OP(acc[mb][0], a00, b0[0]); MFMA_OP(acc[mb][1], a00, b0[1]); \
  MFMA_OP(acc[mb][2], a00, b0[2]); MFMA_OP(acc[mb][3], a00, b0[3]); \
  MFMA_OP(acc[(mb)+1][0], a10, b0[0]); MFMA_OP(acc[(mb)+1][1], a10, b0[1]); \
  MFMA_OP(acc[(mb)+1][2], a10, b0[2]); MFMA_OP(acc[(mb)+1][3], a10, b0[3]); \
  MFMA_OP(acc[mb][0], a01, b1[0]); MFMA_OP(acc[mb][1], a01, b1[1]); \
  MFMA_OP(acc[mb][2], a01, b1[2]); MFMA_OP(acc[mb][3], a01, b1[3]); \
  MFMA_OP(acc[(mb)+1][0], a11, b1[0]); MFMA_OP(acc[(mb)+1][1], a11, b1[1]); \
  MFMA_OP(acc[(mb)+1][2], a11, b1[2]); MFMA_OP(acc[(mb)+1][3], a11, b1[3]); \
  __builtin_amdgcn_s_setprio(0); \
} while (0)

// first phase of a tile: stage was issued by caller; wait tile landed, then
// 12 ds_reads (8 B + 4 A), MFMA m={0,1}.
#define PHASE_FIRST(b) do { \
  VMCNT8; BAR; \
  b0[0] = RD_B(b, 0, 0); b0[1] = RD_B(b, 1, 0); b0[2] = RD_B(b, 2, 0); b0[3] = RD_B(b, 3, 0); \
  b1[0] = RD_B(b, 0, 1); b1[1] = RD_B(b, 1, 1); b1[2] = RD_B(b, 2, 1); b1[3] = RD_B(b, 3, 1); \
  a00 = RD_A(b, 0, 0); a01 = RD_A(b, 0, 1); a10 = RD_A(b, 1, 0); a11 = RD_A(b, 1, 1); \
  MFMA16(0); \
  BAR; \
} while (0)

// later phase: 4 A ds_reads + stage, barrier, MFMA m={mb,mb+1}.
#define PHASE_REST(b, mb, STG) do { \
  a00 = RD_A(b, mb, 0); a01 = RD_A(b, mb, 1); \
  a10 = RD_A(b, (mb)+1, 0); a11 = RD_A(b, (mb)+1, 1); \
  STG; \
  BAR; \
  MFMA16(mb); \
  BAR; \
} while (0)

  // prologue: tile0 (8 loads -> buf0), tile1 partial (6 loads -> buf1)
  STAGE_A(0, 0, 0); STAGE_B(0, 0, 0);
  STAGE_A(0, 1, 0); STAGE_B(0, 1, 0);
  STAGE_A(0, 2, 0); STAGE_B(0, 2, 0);
  STAGE_A(0, 3, 0); STAGE_B(0, 3, 0);
  STAGE_A(1, 0, 64); STAGE_B(1, 0, 64);
  STAGE_A(1, 1, 64); STAGE_B(1, 1, 64);
  STAGE_A(1, 2, 64); STAGE_B(1, 2, 64);

#pragma unroll 1
  for (int it = 0; it < 16; ++it) {
    const int kT1 = it * 128 + 64;                    // tile 2it+1 (real)
    const int kS0 = (it < 15) ? it * 128 + 128 : 0;   // tile 2it+2 (clamped)
    const int kS1 = (it < 15) ? it * 128 + 192 : 0;   // tile 2it+3 (clamped)
    // phase 0: finish staging T1, compute tile 2it m=0,1 from buf0
    STAGE_A(1, 3, kT1); STAGE_B(1, 3, kT1);
    PHASE_FIRST(0);
    // phases 1-3
    PHASE_REST(0, 2, (STAGE_A(0, 0, kS0), STAGE_B(0, 0, kS0)));
    PHASE_REST(0, 4, (STAGE_A(0, 1, kS0), STAGE_B(0, 1, kS0)));
    PHASE_REST(0, 6, (STAGE_A(0, 2, kS0), STAGE_B(0, 2, kS0)));
    // phase 4: finish staging S0, compute tile 2it+1 m=0,1 from buf1
    STAGE_A(0, 3, kS0); STAGE_B(0, 3, kS0);
    PHASE_FIRST(1);
    // phases 5-7
    PHASE_REST(1, 2, (STAGE_A(1, 0, kS1), STAGE_B(1, 0, kS1)));
    PHASE_REST(1, 4, (STAGE_A(1, 1, kS1), STAGE_B(1, 1, kS1)));
    PHASE_REST(1, 6, (STAGE_A(1, 2, kS1), STAGE_B(1, 2, kS1)));
  }

  // drain trailing (garbage) stages before LDS goes out of scope
  asm volatile("s_waitcnt vmcnt(0)" ::: "memory");

  // fused Yat epilogue. C/D: col = lane&15 (N), row = (lane>>4)*4 + reg (M).
  const float scale = powf(sqrtf(8192.0f) / log1pf(8192.0f), alpha[0]);
#pragma unroll
  for (int m = 0; m < 8; ++m) {
#pragma unroll
    for (int r = 0; r < 4; ++r) {
      const size_t grow = rowM0 + wr * 128 + m * 16 + kh * 4 + r;
      const float xq = xs[grow];
      float* orow = out + grow * N_DIM;
#pragma unroll
      for (int n = 0; n < 4; ++n) {
        const int gcol = (int)colN0 + wc * 64 + n * 16 + lr;
        const float y = acc[m][n][r];
        const float d = xq + ks[gcol] - 2.0f * y + EPS_F;
        const float v = y * y * __builtin_amdgcn_rcpf(d);
        orow[gcol] = (v + bias[gcol]) * scale;
      }
    }
  }
}

// ------------------------------ launch -------------------------------------

extern "C" void kernel_launch(void* const* d_in, const int* in_sizes, int n_in,
                              void* d_out, int out_size, void* d_ws, size_t ws_size,
                              hipStream_t stream) {
  const float* x     = (const float*)d_in[0];
  const float* w     = (const float*)d_in[1];
  const float* bias  = (const float*)d_in[2];
  const float* alpha = (const float*)d_in[3];
  float* out = (float*)d_out;
  char* ws = (char*)d_ws;

  unsigned short* xbf = (unsigned short*)(ws);
  unsigned short* ktb = (unsigned short*)(ws + 67108864);
  float* xs    = (float*)(ws + 100663296);
  float* ks    = (float*)(ws + 100728832);
  float* kpart = (float*)(ws + 100761600);

  k_conv_x<<<M_DIM, 256, 0, stream>>>(x, xbf, xs);
  k_conv_kT<<<dim3(N_DIM / 32, K_DIM / 32), dim3(32, 8), 0, stream>>>(w, ktb);
  k_ksq_part<<<dim3(N_DIM / 256, 16), 256, 0, stream>>>(w, kpart);
  k_ksq_fin<<<N_DIM / 256, 256, 0, stream>>>(kpart, ks);
  k_gemm<<<(M_DIM / 256) * (N_DIM / 256), 512, 0, stream>>>(xbf, ktb, xs, ks, bias, alpha, out);
}